// Round 4
// baseline (3063.880 us; speedup 1.0000x reference)
//
#include <hip/hip_runtime.h>
#include <cstdint>
#include <cstddef>

// GPT2-MLA forward, MI355X. Round 4: single-buffered 32KB-LDS GEMM (4 blocks/CU),
// bijective XCD-chunked block swizzle; MFMA flash-attention unchanged.
// B=2, T=1024, D=768, L=12, H=12, HD=64, DL=256, V=50257 (pad 50304)

typedef unsigned short ushortT;
typedef __bf16 bf16x8 __attribute__((ext_vector_type(8)));
typedef float f32x4 __attribute__((ext_vector_type(4)));
typedef unsigned short us8 __attribute__((ext_vector_type(8)));

#define NHEAD 12
#define T_SEQ 1024

__device__ __forceinline__ float bf2f(unsigned short u) {
    union { unsigned int i; float f; } v; v.i = ((unsigned int)u) << 16; return v.f;
}
__device__ __forceinline__ unsigned short f2bf(float f) {
    union { float f; unsigned int i; } v; v.f = f;
    unsigned int r = v.i + 0x7fffu + ((v.i >> 16) & 1u);
    return (unsigned short)(r >> 16);
}
__device__ __forceinline__ unsigned int pack2(float a, float b) {
    return (unsigned int)f2bf(a) | ((unsigned int)f2bf(b) << 16);
}
__device__ __forceinline__ void gload_lds16(const void* g, void* l) {
    __builtin_amdgcn_global_load_lds((__attribute__((address_space(1))) void*)g,
                                     (__attribute__((address_space(3))) void*)l, 16, 0, 0);
}

// ---------------- weight convert / transpose ----------------
__global__ void transpose_cvt_kernel(const float* __restrict__ in, ushortT* __restrict__ outp,
                                     int K, int N, int outRowOff, size_t outLS) {
    __shared__ float tile[32][33];
    const int tx = threadIdx.x, ty = threadIdx.y;
    const int n0 = blockIdx.x * 32, k0 = blockIdx.y * 32;
    const float* src = in + (size_t)blockIdx.z * K * N;
#pragma unroll
    for (int j = 0; j < 4; ++j)
        tile[ty + j * 8][tx] = src[(size_t)(k0 + ty + j * 8) * N + n0 + tx];
    __syncthreads();
    ushortT* dst = outp + (size_t)blockIdx.z * outLS;
#pragma unroll
    for (int j = 0; j < 4; ++j)
        dst[(size_t)(outRowOff + n0 + ty + j * 8) * K + k0 + tx] = f2bf(tile[tx][ty + j * 8]);
}

__global__ void cvt_wte_kernel(const float* __restrict__ in, ushortT* __restrict__ outp) {
    size_t i4 = (size_t)blockIdx.x * 256 + threadIdx.x;
    ushort4 o;
    if (i4 < 9649344) {
        float4 v = ((const float4*)in)[i4];
        o.x = f2bf(v.x); o.y = f2bf(v.y); o.z = f2bf(v.z); o.w = f2bf(v.w);
    } else { o.x = 0; o.y = 0; o.z = 0; o.w = 0; }
    ((ushort4*)outp)[i4] = o;
}

// ---------------- embedding ----------------
__global__ void embed_kernel(const int* __restrict__ idx, const float* __restrict__ wte,
                             const float* __restrict__ wpe, float* __restrict__ x) {
    int i = blockIdx.x * 256 + threadIdx.x;
    int row = i / 768, d = i - row * 768;
    int t = row & 1023;
    x[i] = wte[(size_t)idx[row] * 768 + d] + wpe[(size_t)t * 768 + d];
}

// ---------------- rope ----------------
__global__ void rope_tables_kernel(float* __restrict__ cosT, float* __restrict__ sinT) {
    int i = blockIdx.x * 256 + threadIdx.x;  // 1024*32
    int t = i >> 5, f = i & 31;
    float invf = exp2f(-(float)f * (13.287712379549449f / 32.0f));
    float ang = (float)t * invf;
    cosT[i] = cosf(ang);
    sinT[i] = sinf(ang);
}

__global__ void rope_apply2_kernel(ushortT* __restrict__ qb_, ushortT* __restrict__ kb_,
                                   const float* __restrict__ cosT, const float* __restrict__ sinT) {
    int i = blockIdx.x * 256 + threadIdx.x;  // 2 * 2048*384
    int which = (i >= 786432);
    int ii = i - which * 786432;
    ushortT* x = which ? kb_ : qb_;
    int row = ii / 384, r = ii - row * 384;
    int h = r >> 5, f = r & 31;
    int t = row & 1023;
    size_t base = (size_t)row * 768 + h * 64 + f;
    float x1 = bf2f(x[base]), x2 = bf2f(x[base + 32]);
    float c = cosT[t * 32 + f], s = sinT[t * 32 + f];
    x[base] = f2bf(x1 * c - x2 * s);
    x[base + 32] = f2bf(x2 * c + x1 * s);
}

// ---------------- layernorm ----------------
__global__ __launch_bounds__(256) void ln_kernel(const float* __restrict__ x,
                                                 const float* __restrict__ wg,
                                                 const float* __restrict__ bg,
                                                 ushortT* __restrict__ outp) {
    const int row = blockIdx.x, tid = threadIdx.x;
    const float* xr = x + (size_t)row * 768;
    float v0 = xr[tid], v1 = xr[tid + 256], v2 = xr[tid + 512];
    float s = v0 + v1 + v2;
    float ss = v0 * v0 + v1 * v1 + v2 * v2;
#pragma unroll
    for (int off = 32; off >= 1; off >>= 1) {
        s += __shfl_xor(s, off);
        ss += __shfl_xor(ss, off);
    }
    __shared__ float sb[4], ssb[4];
    if ((tid & 63) == 0) { sb[tid >> 6] = s; ssb[tid >> 6] = ss; }
    __syncthreads();
    float S = sb[0] + sb[1] + sb[2] + sb[3];
    float SS = ssb[0] + ssb[1] + ssb[2] + ssb[3];
    const float mean = S * (1.0f / 768.0f);
    float var = SS * (1.0f / 768.0f) - mean * mean;
    const float rs = rsqrtf(var + 1e-5f);
    ushortT* orow = outp + (size_t)row * 768;
    orow[tid]       = f2bf((v0 - mean) * rs * wg[tid]       + bg[tid]);
    orow[tid + 256] = f2bf((v1 - mean) * rs * wg[tid + 256] + bg[tid + 256]);
    orow[tid + 512] = f2bf((v2 - mean) * rs * wg[tid + 512] + bg[tid + 512]);
}

// ---------------- GEMM: C[2048 x N] = A[2048 x K] @ Bt[N x K]^T ----------------
// BM=128, BN=NF*16, BK=64, single-buffered LDS (16KB + NF*2KB) + XOR swizzle.
// 4 waves stacked in M. Two barriers per K-step (m97 structure); occupancy
// (4 blocks/CU) provides the stage/compute overlap. XCD-chunked block swizzle.
template<int NF>
__global__ __launch_bounds__(256) void gemm128(
    const ushortT* __restrict__ A, int lda,
    const ushortT* __restrict__ Bt, int ldb,
    int K, int CS, int Nstore,
    const float* __restrict__ bias0, const float* __restrict__ bias1,
    ushortT* __restrict__ outB0, int ld0,
    ushortT* __restrict__ outB1, int ld1, int mode1,
    const float* __restrict__ resid, float* __restrict__ outF, int ldF,
    int act) {
    __shared__ __align__(16) char lds[16384 + NF * 2048];
    char* AsB = lds;
    char* BsB = lds + 16384;
    const int tid = threadIdx.x;
    const int w = tid >> 6, lane = tid & 63;
    // bijective XCD-chunked swizzle (m204): dispatch round-robins flat id % 8
    const int gx = gridDim.x;
    const int nwg = gx * gridDim.y;
    const int flat = blockIdx.x + gx * blockIdx.y;
    const int xcd = flat & 7, loc = flat >> 3;
    const int qq = nwg >> 3, rr_ = nwg & 7;
    const int swz = (xcd < rr_ ? xcd * (qq + 1) : rr_ * (qq + 1) + (xcd - rr_) * qq) + loc;
    const int m0 = (swz % gx) * 128, n0 = (swz / gx) * NF * 16;
    const int fr = lane & 15, kg = lane >> 4;
    const size_t ldaB = (size_t)lda * 2, ldbB = (size_t)ldb * 2;
    const char* Ab = (const char*)A;
    const char* Bb = (const char*)Bt;
    f32x4 acc[2][NF] = {};

    auto stage = [&](int t) {
        const size_t ktB = (size_t)t << 7;
#pragma unroll
        for (int jj = 0; jj < 4; ++jj) {
            const int i = tid + jj * 256;
            const int r = i >> 3, c = i & 7, cc = c ^ (r & 7);
            gload_lds16(Ab + (size_t)(m0 + r) * ldaB + ktB + cc * 16, AsB + i * 16);
        }
#pragma unroll
        for (int jj = 0; jj < NF / 2; ++jj) {
            const int i = tid + jj * 256;
            const int r = i >> 3, c = i & 7, cc = c ^ (r & 7);
            gload_lds16(Bb + (size_t)(n0 + r) * ldbB + ktB + cc * 16, BsB + i * 16);
        }
    };

    const int nk = K >> 6;
    for (int t = 0; t < nk; ++t) {
        __syncthreads();
        stage(t);
        __syncthreads();
#pragma unroll
        for (int ks = 0; ks < 2; ++ks) {
            bf16x8 af[2];
#pragma unroll
            for (int mf = 0; mf < 2; ++mf) {
                const int row = w * 32 + mf * 16 + fr;
                af[mf] = *(const bf16x8*)(AsB + row * 128 + (((ks * 4 + kg) ^ (row & 7)) << 4));
            }
#pragma unroll
            for (int nf = 0; nf < NF; ++nf) {
                const int row = nf * 16 + fr;
                bf16x8 bfrag = *(const bf16x8*)(BsB + row * 128 + (((ks * 4 + kg) ^ (row & 7)) << 4));
#pragma unroll
                for (int mf = 0; mf < 2; ++mf)
                    acc[mf][nf] = __builtin_amdgcn_mfma_f32_16x16x32_bf16(
                        af[mf], bfrag, acc[mf][nf], 0, 0, 0);
            }
        }
    }

    // epilogue: frag row = kg*4+j, col = fr
#pragma unroll
    for (int mf = 0; mf < 2; ++mf) {
#pragma unroll
        for (int nf = 0; nf < NF; ++nf) {
            const int gcol = n0 + nf * 16 + fr;
            if (gcol >= Nstore) continue;
            float bv = 0.0f;
            if (gcol < CS) { if (bias0) bv = bias0[gcol]; }
            else           { if (bias1) bv = bias1[gcol - CS]; }
#pragma unroll
            for (int j = 0; j < 4; ++j) {
                const int grow = m0 + w * 32 + mf * 16 + kg * 4 + j;
                float v = acc[mf][nf][j] + bv;
                if (resid) v += resid[(size_t)grow * ldF + gcol];
                if (act) v = 0.5f * v * (1.0f + erff(v * 0.70710678118654752f));
                if (outF) outF[(size_t)grow * ldF + gcol] = v;
                if (gcol < CS) {
                    if (outB0) outB0[(size_t)grow * ld0 + gcol] = f2bf(v);
                } else if (outB1) {
                    if (mode1 == 0) {
                        outB1[(size_t)grow * ld1 + gcol - CS] = f2bf(v);
                    } else {
                        // vT[b][h][d][t]
                        const int bb = grow >> 10, tt = grow & 1023;
                        const int hd = gcol - CS;
                        outB1[((size_t)((bb * 12 + (hd >> 6)) * 64 + (hd & 63)) << 10) + tt] = f2bf(v);
                    }
                }
            }
        }
    }
}

// ---------------- MFMA flash attention ----------------
// Grid (16, 24): x = q-tile of 64 rows, y = (b,h). 4 waves, wave w owns 16 q rows.
// S^T = mfma(Kfrag, Qfrag) -> lane (fr,kg) holds q-row fr's scores (s = n*16+kg*4+j).
// Online softmax per-lane; P exchanged via per-wave LDS row buffer; PV = mfma(P, V^T).
__global__ __launch_bounds__(256) void attn_mfma(const ushortT* __restrict__ q,
                                                 const ushortT* __restrict__ kbuf,
                                                 const ushortT* __restrict__ vT,
                                                 ushortT* __restrict__ attnb) {
    __shared__ __align__(16) char lds[41472];  // K dbuf 16K | V dbuf 16K | P 4x2176
    const int tid = threadIdx.x, w = tid >> 6, lane = tid & 63;
    const int fr = lane & 15, kg = lane >> 4;
    const int b = blockIdx.y / NHEAD, h = blockIdx.y % NHEAD;
    const int qb = blockIdx.x * 64;
    const int q0 = qb + w * 16;
    const int nst = (qb >> 6) + 1, diag = qb >> 6;

    const ushortT* qrow = q + ((size_t)(b * 1024 + q0 + fr) * 768 + h * 64);
    const bf16x8 qf0 = *(const bf16x8*)(qrow + kg * 8);
    const bf16x8 qf1 = *(const bf16x8*)(qrow + 32 + kg * 8);

    const char* kgb = (const char*)kbuf + ((size_t)(b * 1024) * 768 + h * 64) * 2;
    const char* vgb = (const char*)vT + ((size_t)(b * 12 + h) * 65536) * 2;
    char* Pw = lds + 32768 + w * 2176 + fr * 136;

    auto stage = [&](int buf, int st) {
#pragma unroll
        for (int jj = 0; jj < 2; ++jj) {
            const int i = tid + jj * 256;
            const int r = i >> 3, c = i & 7, cc = c ^ (r & 7);
            gload_lds16(kgb + (size_t)(st * 64 + r) * 1536 + cc * 16, lds + buf * 8192 + i * 16);
            gload_lds16(vgb + (size_t)r * 2048 + st * 128 + cc * 16, lds + 16384 + buf * 8192 + i * 16);
        }
    };

    float m_r = -1e30f, l_r = 0.0f;
    f32x4 o[4] = {};

    stage(0, 0);
    __syncthreads();
    for (int st = 0; st < nst; ++st) {
        const int cur = st & 1;
        if (st + 1 < nst) stage(cur ^ 1, st + 1);
        const char* Kd = lds + cur * 8192;
        const char* Vd = lds + 16384 + cur * 8192;

        // S^T frags: sfr[n] rows s = n*16+kg*4+j, col q=fr
        f32x4 sfr[4];
#pragma unroll
        for (int n = 0; n < 4; ++n) {
            const int row = n * 16 + fr;
            bf16x8 k0 = *(const bf16x8*)(Kd + row * 128 + ((kg ^ (row & 7)) << 4));
            bf16x8 k1 = *(const bf16x8*)(Kd + row * 128 + (((4 + kg) ^ (row & 7)) << 4));
            f32x4 sa = {0.0f, 0.0f, 0.0f, 0.0f};
            sa = __builtin_amdgcn_mfma_f32_16x16x32_bf16(k0, qf0, sa, 0, 0, 0);
            sa = __builtin_amdgcn_mfma_f32_16x16x32_bf16(k1, qf1, sa, 0, 0, 0);
            sfr[n] = sa;
        }
        const int qoff = w * 16 + fr;
#pragma unroll
        for (int n = 0; n < 4; ++n)
#pragma unroll
            for (int j = 0; j < 4; ++j) {
                float v = sfr[n][j] * 0.125f;
                if (st == diag && (n * 16 + kg * 4 + j) > qoff) v = -1e30f;
                sfr[n][j] = v;
            }
        // online softmax (state per lane, q = fr)
        float tm = -1e30f;
#pragma unroll
        for (int n = 0; n < 4; ++n)
#pragma unroll
            for (int j = 0; j < 4; ++j) tm = fmaxf(tm, sfr[n][j]);
        tm = fmaxf(tm, __shfl_xor(tm, 16));
        tm = fmaxf(tm, __shfl_xor(tm, 32));
        const float mnew = fmaxf(m_r, tm);
        const float fac = __expf(m_r - mnew);
        m_r = mnew;
        l_r *= fac;
        const float ff0 = __shfl(fac, kg * 4 + 0);
        const float ff1 = __shfl(fac, kg * 4 + 1);
        const float ff2 = __shfl(fac, kg * 4 + 2);
        const float ff3 = __shfl(fac, kg * 4 + 3);
#pragma unroll
        for (int nf = 0; nf < 4; ++nf) {
            o[nf][0] *= ff0; o[nf][1] *= ff1; o[nf][2] *= ff2; o[nf][3] *= ff3;
        }
        // exp, pack to bf16, write P rows to per-wave LDS
#pragma unroll
        for (int n = 0; n < 4; ++n) {
            float e0 = __expf(sfr[n][0] - mnew);
            float e1 = __expf(sfr[n][1] - mnew);
            float e2 = __expf(sfr[n][2] - mnew);
            float e3 = __expf(sfr[n][3] - mnew);
            l_r += (e0 + e1) + (e2 + e3);
            uint2 pv;
            pv.x = pack2(e0, e1);
            pv.y = pack2(e2, e3);
            *(uint2*)(Pw + n * 32 + kg * 8) = pv;
        }
        // PV: A = P[q=fr][s], B = V^T[d][s]
#pragma unroll
        for (int ks = 0; ks < 2; ++ks) {
            uint2 a0 = *(const uint2*)(Pw + ks * 64 + kg * 16);
            uint2 a1 = *(const uint2*)(Pw + ks * 64 + kg * 16 + 8);
            union { uint4 u; bf16x8 v; } pa;
            pa.u = make_uint4(a0.x, a0.y, a1.x, a1.y);
#pragma unroll
            for (int nf = 0; nf < 4; ++nf) {
                const int row = nf * 16 + fr;
                bf16x8 vf = *(const bf16x8*)(Vd + row * 128 + (((ks * 4 + kg) ^ (row & 7)) << 4));
                o[nf] = __builtin_amdgcn_mfma_f32_16x16x32_bf16(pa.v, vf, o[nf], 0, 0, 0);
            }
        }
        __syncthreads();
    }

    l_r += __shfl_xor(l_r, 16);
    l_r += __shfl_xor(l_r, 32);
    const float inv = 1.0f / l_r;
    const float iv0 = __shfl(inv, kg * 4 + 0);
    const float iv1 = __shfl(inv, kg * 4 + 1);
    const float iv2 = __shfl(inv, kg * 4 + 2);
    const float iv3 = __shfl(inv, kg * 4 + 3);
#pragma unroll
    for (int nf = 0; nf < 4; ++nf) {
        const size_t base = (size_t)(b * 1024 + q0) * 768 + h * 64 + nf * 16 + fr;
        attnb[base + (size_t)(kg * 4 + 0) * 768] = f2bf(o[nf][0] * iv0);
        attnb[base + (size_t)(kg * 4 + 1) * 768] = f2bf(o[nf][1] * iv1);
        attnb[base + (size_t)(kg * 4 + 2) * 768] = f2bf(o[nf][2] * iv2);
        attnb[base + (size_t)(kg * 4 + 3) * 768] = f2bf(o[nf][3] * iv3);
    }
}

// ---------------- host ----------------
extern "C" void kernel_launch(void* const* d_in, const int* in_sizes, int n_in,
                              void* d_out, int out_size, void* d_ws, size_t ws_size,
                              hipStream_t stream) {
    (void)in_sizes; (void)n_in; (void)out_size; (void)ws_size;
    const int*   idxp   = (const int*)d_in[0];
    const float* wte    = (const float*)d_in[1];
    const float* wpe    = (const float*)d_in[2];
    const float* ln1_w  = (const float*)d_in[3];
    const float* ln1_b  = (const float*)d_in[4];
    const float* wq_w   = (const float*)d_in[5];
    const float* wq_b   = (const float*)d_in[6];
    const float* kva_w  = (const float*)d_in[7];
    const float* kva_b  = (const float*)d_in[8];
    const float* kvb_w  = (const float*)d_in[9];
    const float* kvb_b  = (const float*)d_in[10];
    const float* out_w  = (const float*)d_in[11];
    const float* out_b  = (const float*)d_in[12];
    const float* ln2_w  = (const float*)d_in[13];
    const float* ln2_b  = (const float*)d_in[14];
    const float* fc_w   = (const float*)d_in[15];
    const float* fc_b   = (const float*)d_in[16];
    const float* proj_w = (const float*)d_in[17];
    const float* proj_b = (const float*)d_in[18];
    const float* lnf_w  = (const float*)d_in[19];
    const float* lnf_b  = (const float*)d_in[20];

    char* ws = (char*)d_ws;
    size_t off = 0;
    auto alloc = [&](size_t bytes) -> char* {
        char* p = ws + off;
        off += (bytes + 255) & ~(size_t)255;
        return p;
    };
    ushortT* wqkvaT = (ushortT*)alloc((size_t)12 * 1024 * 768 * 2);
    ushortT* kvbT   = (ushortT*)alloc((size_t)12 * 1536 * 256 * 2);
    ushortT* outT   = (ushortT*)alloc((size_t)12 * 768 * 768 * 2);
    ushortT* fcT    = (ushortT*)alloc((size_t)12 * 3072 * 768 * 2);
    ushortT* projT  = (ushortT*)alloc((size_t)12 * 768 * 3072 * 2);
    ushortT* wteB   = (ushortT*)alloc((size_t)50304 * 768 * 2);
    float* cosT = (float*)alloc((size_t)1024 * 32 * 4);
    float* sinT = (float*)alloc((size_t)1024 * 32 * 4);
    float*   x     = (float*)alloc((size_t)2048 * 768 * 4);
    ushortT* h     = (ushortT*)alloc((size_t)2048 * 768 * 2);
    ushortT* qbuf  = (ushortT*)alloc((size_t)2048 * 768 * 2);
    ushortT* lat   = (ushortT*)alloc((size_t)2048 * 256 * 2);
    ushortT* kvbuf = (ushortT*)alloc((size_t)2048 * 768 * 2);   // K only
    ushortT* vTb   = (ushortT*)alloc((size_t)24 * 64 * 1024 * 2);  // [b][h][d][t]
    ushortT* attnb = (ushortT*)alloc((size_t)2048 * 768 * 2);
    ushortT* fca   = (ushortT*)alloc((size_t)2048 * 3072 * 2);

    const dim3 blkT(32, 8);
    transpose_cvt_kernel<<<dim3(24, 24, 12), blkT, 0, stream>>>(wq_w,  wqkvaT, 768, 768,  0,   (size_t)1024 * 768);
    transpose_cvt_kernel<<<dim3(8,  24, 12), blkT, 0, stream>>>(kva_w, wqkvaT, 768, 256,  768, (size_t)1024 * 768);
    transpose_cvt_kernel<<<dim3(48, 8,  12), blkT, 0, stream>>>(kvb_w, kvbT,   256, 1536, 0,   (size_t)1536 * 256);
    transpose_cvt_kernel<<<dim3(24, 24, 12), blkT, 0, stream>>>(out_w, outT,   768, 768,  0,   (size_t)768 * 768);
    transpose_cvt_kernel<<<dim3(96, 24, 12), blkT, 0, stream>>>(fc_w,  fcT,    768, 3072, 0,   (size_t)3072 * 768);
    transpose_cvt_kernel<<<dim3(24, 96, 12), blkT, 0, stream>>>(proj_w, projT, 3072, 768, 0,   (size_t)768 * 3072);
    cvt_wte_kernel<<<37728, 256, 0, stream>>>(wte, wteB);
    rope_tables_kernel<<<128, 256, 0, stream>>>(cosT, sinT);
    embed_kernel<<<6144, 256, 0, stream>>>(idxp, wte, wpe, x);

    for (int l = 0; l < 12; ++l) {
        ln_kernel<<<2048, 256, 0, stream>>>(x, ln1_w + l * 768, ln1_b + l * 768, h);
        // fused q | kv_latent
        gemm128<8><<<dim3(16, 8), 256, 0, stream>>>(
            h, 768, wqkvaT + (size_t)l * 1024 * 768, 768,
            768, 768, 1024, wq_b + l * 768, kva_b + l * 256,
            qbuf, 768, lat, 256, 0, nullptr, nullptr, 0, 0);
        // kv = lat @ kvb: K part -> kvbuf rows, V part -> vT transposed
        gemm128<8><<<dim3(16, 12), 256, 0, stream>>>(
            lat, 256, kvbT + (size_t)l * 1536 * 256, 256,
            256, 768, 1536, kvb_b + l * 1536, kvb_b + l * 1536 + 768,
            kvbuf, 768, vTb, 0, 1, nullptr, nullptr, 0, 0);
        rope_apply2_kernel<<<6144, 256, 0, stream>>>(qbuf, kvbuf, cosT, sinT);
        attn_mfma<<<dim3(16, 24), 256, 0, stream>>>(qbuf, kvbuf, vTb, attnb);
        gemm128<4><<<dim3(16, 12), 256, 0, stream>>>(
            attnb, 768, outT + (size_t)l * 768 * 768, 768,
            768, 768, 768, out_b + l * 768, nullptr,
            nullptr, 0, nullptr, 0, 0, x, x, 768, 0);
        ln_kernel<<<2048, 256, 0, stream>>>(x, ln2_w + l * 768, ln2_b + l * 768, h);
        gemm128<8><<<dim3(16, 24), 256, 0, stream>>>(
            h, 768, fcT + (size_t)l * 3072 * 768, 768,
            768, 3072, 3072, fc_b + l * 3072, nullptr,
            fca, 3072, nullptr, 0, 0, nullptr, nullptr, 0, 1);
        gemm128<4><<<dim3(16, 12), 256, 0, stream>>>(
            fca, 3072, projT + (size_t)l * 768 * 3072, 3072,
            3072, 768, 768, proj_b + l * 768, nullptr,
            nullptr, 0, nullptr, 0, 0, x, x, 768, 0);
    }
    ln_kernel<<<2048, 256, 0, stream>>>(x, lnf_w, lnf_b, h);
    gemm128<8><<<dim3(16, 393), 256, 0, stream>>>(
        h, 768, wteB, 768,
        768, 50304, 50257, nullptr, nullptr,
        nullptr, 0, nullptr, 0, 0, nullptr, (float*)d_out, 50257, 0);
}

// Round 5
// 2264.428 us; speedup vs baseline: 1.3530x; 1.3530x over previous
//
#include <hip/hip_runtime.h>
#include <cstdint>
#include <cstddef>

// GPT2-MLA forward, MI355X. Round 5: 2-deep prefetch GEMM with counted vmcnt
// (raw s_barrier, never drains the prefetch queue), per-shape tiles.
// B=2, T=1024, D=768, L=12, H=12, HD=64, DL=256, V=50257 (pad 50304)

typedef unsigned short ushortT;
typedef __bf16 bf16x8 __attribute__((ext_vector_type(8)));
typedef float f32x4 __attribute__((ext_vector_type(4)));
typedef unsigned short us8 __attribute__((ext_vector_type(8)));

#define NHEAD 12
#define T_SEQ 1024

__device__ __forceinline__ float bf2f(unsigned short u) {
    union { unsigned int i; float f; } v; v.i = ((unsigned int)u) << 16; return v.f;
}
__device__ __forceinline__ unsigned short f2bf(float f) {
    union { float f; unsigned int i; } v; v.f = f;
    unsigned int r = v.i + 0x7fffu + ((v.i >> 16) & 1u);
    return (unsigned short)(r >> 16);
}
__device__ __forceinline__ unsigned int pack2(float a, float b) {
    return (unsigned int)f2bf(a) | ((unsigned int)f2bf(b) << 16);
}
__device__ __forceinline__ void gload_lds16(const void* g, void* l) {
    __builtin_amdgcn_global_load_lds((__attribute__((address_space(1))) void*)g,
                                     (__attribute__((address_space(3))) void*)l, 16, 0, 0);
}
template <int N>
__device__ __forceinline__ void wait_vmcnt() {
    if constexpr (N == 8)      asm volatile("s_waitcnt vmcnt(8)" ::: "memory");
    else if constexpr (N == 6) asm volatile("s_waitcnt vmcnt(6)" ::: "memory");
    else if constexpr (N == 4) asm volatile("s_waitcnt vmcnt(4)" ::: "memory");
    else                       asm volatile("s_waitcnt vmcnt(0)" ::: "memory");
}

// ---------------- weight convert / transpose ----------------
__global__ void transpose_cvt_kernel(const float* __restrict__ in, ushortT* __restrict__ outp,
                                     int K, int N, int outRowOff, size_t outLS) {
    __shared__ float tile[32][33];
    const int tx = threadIdx.x, ty = threadIdx.y;
    const int n0 = blockIdx.x * 32, k0 = blockIdx.y * 32;
    const float* src = in + (size_t)blockIdx.z * K * N;
#pragma unroll
    for (int j = 0; j < 4; ++j)
        tile[ty + j * 8][tx] = src[(size_t)(k0 + ty + j * 8) * N + n0 + tx];
    __syncthreads();
    ushortT* dst = outp + (size_t)blockIdx.z * outLS;
#pragma unroll
    for (int j = 0; j < 4; ++j)
        dst[(size_t)(outRowOff + n0 + ty + j * 8) * K + k0 + tx] = f2bf(tile[tx][ty + j * 8]);
}

__global__ void cvt_wte_kernel(const float* __restrict__ in, ushortT* __restrict__ outp) {
    size_t i4 = (size_t)blockIdx.x * 256 + threadIdx.x;
    ushort4 o;
    if (i4 < 9649344) {
        float4 v = ((const float4*)in)[i4];
        o.x = f2bf(v.x); o.y = f2bf(v.y); o.z = f2bf(v.z); o.w = f2bf(v.w);
    } else { o.x = 0; o.y = 0; o.z = 0; o.w = 0; }
    ((ushort4*)outp)[i4] = o;
}

// ---------------- embedding ----------------
__global__ void embed_kernel(const int* __restrict__ idx, const float* __restrict__ wte,
                             const float* __restrict__ wpe, float* __restrict__ x) {
    int i = blockIdx.x * 256 + threadIdx.x;
    int row = i / 768, d = i - row * 768;
    int t = row & 1023;
    x[i] = wte[(size_t)idx[row] * 768 + d] + wpe[(size_t)t * 768 + d];
}

// ---------------- rope ----------------
__global__ void rope_tables_kernel(float* __restrict__ cosT, float* __restrict__ sinT) {
    int i = blockIdx.x * 256 + threadIdx.x;  // 1024*32
    int t = i >> 5, f = i & 31;
    float invf = exp2f(-(float)f * (13.287712379549449f / 32.0f));
    float ang = (float)t * invf;
    cosT[i] = cosf(ang);
    sinT[i] = sinf(ang);
}

__global__ void rope_apply2_kernel(ushortT* __restrict__ qb_, ushortT* __restrict__ kb_,
                                   const float* __restrict__ cosT, const float* __restrict__ sinT) {
    int i = blockIdx.x * 256 + threadIdx.x;  // 2 * 2048*384
    int which = (i >= 786432);
    int ii = i - which * 786432;
    ushortT* x = which ? kb_ : qb_;
    int row = ii / 384, r = ii - row * 384;
    int h = r >> 5, f = r & 31;
    int t = row & 1023;
    size_t base = (size_t)row * 768 + h * 64 + f;
    float x1 = bf2f(x[base]), x2 = bf2f(x[base + 32]);
    float c = cosT[t * 32 + f], s = sinT[t * 32 + f];
    x[base] = f2bf(x1 * c - x2 * s);
    x[base + 32] = f2bf(x2 * c + x1 * s);
}

// ---------------- layernorm ----------------
__global__ __launch_bounds__(256) void ln_kernel(const float* __restrict__ x,
                                                 const float* __restrict__ wg,
                                                 const float* __restrict__ bg,
                                                 ushortT* __restrict__ outp) {
    const int row = blockIdx.x, tid = threadIdx.x;
    const float* xr = x + (size_t)row * 768;
    float v0 = xr[tid], v1 = xr[tid + 256], v2 = xr[tid + 512];
    float s = v0 + v1 + v2;
    float ss = v0 * v0 + v1 * v1 + v2 * v2;
#pragma unroll
    for (int off = 32; off >= 1; off >>= 1) {
        s += __shfl_xor(s, off);
        ss += __shfl_xor(ss, off);
    }
    __shared__ float sb[4], ssb[4];
    if ((tid & 63) == 0) { sb[tid >> 6] = s; ssb[tid >> 6] = ss; }
    __syncthreads();
    float S = sb[0] + sb[1] + sb[2] + sb[3];
    float SS = ssb[0] + ssb[1] + ssb[2] + ssb[3];
    const float mean = S * (1.0f / 768.0f);
    float var = SS * (1.0f / 768.0f) - mean * mean;
    const float rs = rsqrtf(var + 1e-5f);
    ushortT* orow = outp + (size_t)row * 768;
    orow[tid]       = f2bf((v0 - mean) * rs * wg[tid]       + bg[tid]);
    orow[tid + 256] = f2bf((v1 - mean) * rs * wg[tid + 256] + bg[tid + 256]);
    orow[tid + 512] = f2bf((v2 - mean) * rs * wg[tid + 512] + bg[tid + 512]);
}

// ---------------- GEMM: C[2048 x N] = A[2048 x K] @ Bt[N x K]^T ----------------
// BM x (NF*16) tile, BK=64, 4 waves stacked in M (BM/4 rows each). Double-buffered
// LDS + XOR swizzle. 2-deep prefetch with COUNTED vmcnt (raw s_barrier): tile t+2
// stays in flight across the barrier; only t+1 is waited (T3+T4). XCD-chunked swizzle.
template <int BM, int NF>
__global__ __launch_bounds__(256) void gemmT(
    const ushortT* __restrict__ A, int lda,
    const ushortT* __restrict__ Bt, int ldb,
    int K, int CS, int Nstore,
    const float* __restrict__ bias0, const float* __restrict__ bias1,
    ushortT* __restrict__ outB0, int ld0,
    ushortT* __restrict__ outB1, int ld1, int mode1,
    const float* __restrict__ resid, float* __restrict__ outF, int ldF,
    int act) {
    constexpr int WM = BM / 4;         // rows per wave
    constexpr int MF = WM / 16;        // m-frags per wave
    constexpr int ABYTES = BM * 128;   // per-buffer A bytes (BK=64)
    constexpr int BBYTES = NF * 2048;
    constexpr int BUFB = ABYTES + BBYTES;
    constexpr int S = (BM == 128 ? 4 : 2) + NF / 2;  // stage loads per thread
    __shared__ __align__(16) char lds[2 * BUFB];
    const int tid = threadIdx.x;
    const int w = tid >> 6, lane = tid & 63;
    // bijective XCD-chunked swizzle (m204)
    const int gx = gridDim.x;
    const int nwg = gx * gridDim.y;
    const int flat = blockIdx.x + gx * blockIdx.y;
    const int xcd = flat & 7, loc = flat >> 3;
    const int qq = nwg >> 3, rr_ = nwg & 7;
    const int swz = (xcd < rr_ ? xcd * (qq + 1) : rr_ * (qq + 1) + (xcd - rr_) * qq) + loc;
    const int m0 = (swz % gx) * BM, n0 = (swz / gx) * NF * 16;
    const int fr = lane & 15, kg = lane >> 4;
    const size_t ldaB = (size_t)lda * 2, ldbB = (size_t)ldb * 2;
    const char* Ab = (const char*)A;
    const char* Bb = (const char*)Bt;
    f32x4 acc[MF][NF] = {};

    auto stage = [&](int buf, int t) {
        const size_t ktB = (size_t)t << 7;
        char* As_ = lds + buf * BUFB;
        char* Bs_ = As_ + ABYTES;
#pragma unroll
        for (int jj = 0; jj < BM / 32; ++jj) {
            const int i = tid + jj * 256;
            const int r = i >> 3, c = i & 7, cc = c ^ (r & 7);
            gload_lds16(Ab + (size_t)(m0 + r) * ldaB + ktB + cc * 16, As_ + i * 16);
        }
#pragma unroll
        for (int jj = 0; jj < NF / 2; ++jj) {
            const int i = tid + jj * 256;
            const int r = i >> 3, c = i & 7, cc = c ^ (r & 7);
            gload_lds16(Bb + (size_t)(n0 + r) * ldbB + ktB + cc * 16, Bs_ + i * 16);
        }
    };

    const int nk = K >> 6;
    stage(0, 0);
    if (nk > 1) { stage(1, 1); wait_vmcnt<S>(); }
    else        { wait_vmcnt<0>(); }
    __builtin_amdgcn_s_barrier();

    for (int t = 0; t < nk; ++t) {
        const int cur = t & 1;
        const char* As_ = lds + cur * BUFB;
        const char* Bs_ = As_ + ABYTES;
        bf16x8 af[MF][2], bfr[NF][2];
#pragma unroll
        for (int mf = 0; mf < MF; ++mf) {
            const int row = w * WM + mf * 16 + fr;
#pragma unroll
            for (int ks = 0; ks < 2; ++ks)
                af[mf][ks] = *(const bf16x8*)(As_ + row * 128 + (((ks * 4 + kg) ^ (row & 7)) << 4));
        }
#pragma unroll
        for (int nf = 0; nf < NF; ++nf) {
            const int row = nf * 16 + fr;
#pragma unroll
            for (int ks = 0; ks < 2; ++ks)
                bfr[nf][ks] = *(const bf16x8*)(Bs_ + row * 128 + (((ks * 4 + kg) ^ (row & 7)) << 4));
        }
        if (t + 2 < nk) {
            asm volatile("s_waitcnt lgkmcnt(0)" ::: "memory");  // reads of buf[cur] done
            __builtin_amdgcn_s_barrier();                       // ... in ALL waves
            stage(cur, t + 2);                                  // overwrite buf[cur]
        }
#pragma unroll
        for (int ks = 0; ks < 2; ++ks)
#pragma unroll
            for (int nf = 0; nf < NF; ++nf)
#pragma unroll
                for (int mf = 0; mf < MF; ++mf)
                    acc[mf][nf] = __builtin_amdgcn_mfma_f32_16x16x32_bf16(
                        af[mf][ks], bfr[nf][ks], acc[mf][nf], 0, 0, 0);
        if (t + 1 < nk) {
            if (t + 2 < nk) wait_vmcnt<S>();  // t+1 landed; t+2 stays in flight
            else            wait_vmcnt<0>();
            __builtin_amdgcn_s_barrier();
        }
    }

    // epilogue: frag row = kg*4+j, col = fr
#pragma unroll
    for (int mf = 0; mf < MF; ++mf) {
#pragma unroll
        for (int nf = 0; nf < NF; ++nf) {
            const int gcol = n0 + nf * 16 + fr;
            if (gcol >= Nstore) continue;
            float bv = 0.0f;
            if (gcol < CS) { if (bias0) bv = bias0[gcol]; }
            else           { if (bias1) bv = bias1[gcol - CS]; }
#pragma unroll
            for (int j = 0; j < 4; ++j) {
                const int grow = m0 + w * WM + mf * 16 + kg * 4 + j;
                float v = acc[mf][nf][j] + bv;
                if (resid) v += resid[(size_t)grow * ldF + gcol];
                if (act) v = 0.5f * v * (1.0f + erff(v * 0.70710678118654752f));
                if (outF) outF[(size_t)grow * ldF + gcol] = v;
                if (gcol < CS) {
                    if (outB0) outB0[(size_t)grow * ld0 + gcol] = f2bf(v);
                } else if (outB1) {
                    if (mode1 == 0) {
                        outB1[(size_t)grow * ld1 + gcol - CS] = f2bf(v);
                    } else {
                        // vT[b][h][d][t]
                        const int bb = grow >> 10, tt = grow & 1023;
                        const int hd = gcol - CS;
                        outB1[((size_t)((bb * 12 + (hd >> 6)) * 64 + (hd & 63)) << 10) + tt] = f2bf(v);
                    }
                }
            }
        }
    }
}

// ---------------- MFMA flash attention ----------------
// Grid (16, 24): x = q-tile of 64 rows, y = (b,h). 4 waves, wave w owns 16 q rows.
// S^T = mfma(Kfrag, Qfrag) -> lane (fr,kg) holds q-row fr's scores (s = n*16+kg*4+j).
// Online softmax per-lane; P exchanged via per-wave LDS row buffer; PV = mfma(P, V^T).
__global__ __launch_bounds__(256) void attn_mfma(const ushortT* __restrict__ q,
                                                 const ushortT* __restrict__ kbuf,
                                                 const ushortT* __restrict__ vT,
                                                 ushortT* __restrict__ attnb) {
    __shared__ __align__(16) char lds[41472];  // K dbuf 16K | V dbuf 16K | P 4x2176
    const int tid = threadIdx.x, w = tid >> 6, lane = tid & 63;
    const int fr = lane & 15, kg = lane >> 4;
    const int b = blockIdx.y / NHEAD, h = blockIdx.y % NHEAD;
    const int qb = blockIdx.x * 64;
    const int q0 = qb + w * 16;
    const int nst = (qb >> 6) + 1, diag = qb >> 6;

    const ushortT* qrow = q + ((size_t)(b * 1024 + q0 + fr) * 768 + h * 64);
    const bf16x8 qf0 = *(const bf16x8*)(qrow + kg * 8);
    const bf16x8 qf1 = *(const bf16x8*)(qrow + 32 + kg * 8);

    const char* kgb = (const char*)kbuf + ((size_t)(b * 1024) * 768 + h * 64) * 2;
    const char* vgb = (const char*)vT + ((size_t)(b * 12 + h) * 65536) * 2;
    char* Pw = lds + 32768 + w * 2176 + fr * 136;

    auto stage = [&](int buf, int st) {
#pragma unroll
        for (int jj = 0; jj < 2; ++jj) {
            const int i = tid + jj * 256;
            const int r = i >> 3, c = i & 7, cc = c ^ (r & 7);
            gload_lds16(kgb + (size_t)(st * 64 + r) * 1536 + cc * 16, lds + buf * 8192 + i * 16);
            gload_lds16(vgb + (size_t)r * 2048 + st * 128 + cc * 16, lds + 16384 + buf * 8192 + i * 16);
        }
    };

    float m_r = -1e30f, l_r = 0.0f;
    f32x4 o[4] = {};

    stage(0, 0);
    __syncthreads();
    for (int st = 0; st < nst; ++st) {
        const int cur = st & 1;
        if (st + 1 < nst) stage(cur ^ 1, st + 1);
        const char* Kd = lds + cur * 8192;
        const char* Vd = lds + 16384 + cur * 8192;

        // S^T frags: sfr[n] rows s = n*16+kg*4+j, col q=fr
        f32x4 sfr[4];
#pragma unroll
        for (int n = 0; n < 4; ++n) {
            const int row = n * 16 + fr;
            bf16x8 k0 = *(const bf16x8*)(Kd + row * 128 + ((kg ^ (row & 7)) << 4));
            bf16x8 k1 = *(const bf16x8*)(Kd + row * 128 + (((4 + kg) ^ (row & 7)) << 4));
            f32x4 sa = {0.0f, 0.0f, 0.0f, 0.0f};
            sa = __builtin_amdgcn_mfma_f32_16x16x32_bf16(k0, qf0, sa, 0, 0, 0);
            sa = __builtin_amdgcn_mfma_f32_16x16x32_bf16(k1, qf1, sa, 0, 0, 0);
            sfr[n] = sa;
        }
        const int qoff = w * 16 + fr;
#pragma unroll
        for (int n = 0; n < 4; ++n)
#pragma unroll
            for (int j = 0; j < 4; ++j) {
                float v = sfr[n][j] * 0.125f;
                if (st == diag && (n * 16 + kg * 4 + j) > qoff) v = -1e30f;
                sfr[n][j] = v;
            }
        // online softmax (state per lane, q = fr)
        float tm = -1e30f;
#pragma unroll
        for (int n = 0; n < 4; ++n)
#pragma unroll
            for (int j = 0; j < 4; ++j) tm = fmaxf(tm, sfr[n][j]);
        tm = fmaxf(tm, __shfl_xor(tm, 16));
        tm = fmaxf(tm, __shfl_xor(tm, 32));
        const float mnew = fmaxf(m_r, tm);
        const float fac = __expf(m_r - mnew);
        m_r = mnew;
        l_r *= fac;
        const float ff0 = __shfl(fac, kg * 4 + 0);
        const float ff1 = __shfl(fac, kg * 4 + 1);
        const float ff2 = __shfl(fac, kg * 4 + 2);
        const float ff3 = __shfl(fac, kg * 4 + 3);
#pragma unroll
        for (int nf = 0; nf < 4; ++nf) {
            o[nf][0] *= ff0; o[nf][1] *= ff1; o[nf][2] *= ff2; o[nf][3] *= ff3;
        }
        // exp, pack to bf16, write P rows to per-wave LDS
#pragma unroll
        for (int n = 0; n < 4; ++n) {
            float e0 = __expf(sfr[n][0] - mnew);
            float e1 = __expf(sfr[n][1] - mnew);
            float e2 = __expf(sfr[n][2] - mnew);
            float e3 = __expf(sfr[n][3] - mnew);
            l_r += (e0 + e1) + (e2 + e3);
            uint2 pv;
            pv.x = pack2(e0, e1);
            pv.y = pack2(e2, e3);
            *(uint2*)(Pw + n * 32 + kg * 8) = pv;
        }
        // PV: A = P[q=fr][s], B = V^T[d][s]
#pragma unroll
        for (int ks = 0; ks < 2; ++ks) {
            uint2 a0 = *(const uint2*)(Pw + ks * 64 + kg * 16);
            uint2 a1 = *(const uint2*)(Pw + ks * 64 + kg * 16 + 8);
            union { uint4 u; bf16x8 v; } pa;
            pa.u = make_uint4(a0.x, a0.y, a1.x, a1.y);
#pragma unroll
            for (int nf = 0; nf < 4; ++nf) {
                const int row = nf * 16 + fr;
                bf16x8 vf = *(const bf16x8*)(Vd + row * 128 + (((ks * 4 + kg) ^ (row & 7)) << 4));
                o[nf] = __builtin_amdgcn_mfma_f32_16x16x32_bf16(pa.v, vf, o[nf], 0, 0, 0);
            }
        }
        __syncthreads();
    }

    l_r += __shfl_xor(l_r, 16);
    l_r += __shfl_xor(l_r, 32);
    const float inv = 1.0f / l_r;
    const float iv0 = __shfl(inv, kg * 4 + 0);
    const float iv1 = __shfl(inv, kg * 4 + 1);
    const float iv2 = __shfl(inv, kg * 4 + 2);
    const float iv3 = __shfl(inv, kg * 4 + 3);
#pragma unroll
    for (int nf = 0; nf < 4; ++nf) {
        const size_t base = (size_t)(b * 1024 + q0) * 768 + h * 64 + nf * 16 + fr;
        attnb[base + (size_t)(kg * 4 + 0) * 768] = f2bf(o[nf][0] * iv0);
        attnb[base + (size_t)(kg * 4 + 1) * 768] = f2bf(o[nf][1] * iv1);
        attnb[base + (size_t)(kg * 4 + 2) * 768] = f2bf(o[nf][2] * iv2);
        attnb[base + (size_t)(kg * 4 + 3) * 768] = f2bf(o[nf][3] * iv3);
    }
}

// ---------------- host ----------------
extern "C" void kernel_launch(void* const* d_in, const int* in_sizes, int n_in,
                              void* d_out, int out_size, void* d_ws, size_t ws_size,
                              hipStream_t stream) {
    (void)in_sizes; (void)n_in; (void)out_size; (void)ws_size;
    const int*   idxp   = (const int*)d_in[0];
    const float* wte    = (const float*)d_in[1];
    const float* wpe    = (const float*)d_in[2];
    const float* ln1_w  = (const float*)d_in[3];
    const float* ln1_b  = (const float*)d_in[4];
    const float* wq_w   = (const float*)d_in[5];
    const float* wq_b   = (const float*)d_in[6];
    const float* kva_w  = (const float*)d_in[7];
    const float* kva_b  = (const float*)d_in[8];
    const float* kvb_w  = (const float*)d_in[9];
    const float* kvb_b  = (const float*)d_in[10];
    const float* out_w  = (const float*)d_in[11];
    const float* out_b  = (const float*)d_in[12];
    const float* ln2_w  = (const float*)d_in[13];
    const float* ln2_b  = (const float*)d_in[14];
    const float* fc_w   = (const float*)d_in[15];
    const float* fc_b   = (const float*)d_in[16];
    const float* proj_w = (const float*)d_in[17];
    const float* proj_b = (const float*)d_in[18];
    const float* lnf_w  = (const float*)d_in[19];
    const float* lnf_b  = (const float*)d_in[20];

    char* ws = (char*)d_ws;
    size_t off = 0;
    auto alloc = [&](size_t bytes) -> char* {
        char* p = ws + off;
        off += (bytes + 255) & ~(size_t)255;
        return p;
    };
    ushortT* wqkvaT = (ushortT*)alloc((size_t)12 * 1024 * 768 * 2);
    ushortT* kvbT   = (ushortT*)alloc((size_t)12 * 1536 * 256 * 2);
    ushortT* outT   = (ushortT*)alloc((size_t)12 * 768 * 768 * 2);
    ushortT* fcT    = (ushortT*)alloc((size_t)12 * 3072 * 768 * 2);
    ushortT* projT  = (ushortT*)alloc((size_t)12 * 768 * 3072 * 2);
    ushortT* wteB   = (ushortT*)alloc((size_t)50304 * 768 * 2);
    float* cosT = (float*)alloc((size_t)1024 * 32 * 4);
    float* sinT = (float*)alloc((size_t)1024 * 32 * 4);
    float*   x     = (float*)alloc((size_t)2048 * 768 * 4);
    ushortT* h     = (ushortT*)alloc((size_t)2048 * 768 * 2);
    ushortT* qbuf  = (ushortT*)alloc((size_t)2048 * 768 * 2);
    ushortT* lat   = (ushortT*)alloc((size_t)2048 * 256 * 2);
    ushortT* kvbuf = (ushortT*)alloc((size_t)2048 * 768 * 2);   // K only
    ushortT* vTb   = (ushortT*)alloc((size_t)24 * 64 * 1024 * 2);  // [b][h][d][t]
    ushortT* attnb = (ushortT*)alloc((size_t)2048 * 768 * 2);
    ushortT* fca   = (ushortT*)alloc((size_t)2048 * 3072 * 2);

    const dim3 blkT(32, 8);
    transpose_cvt_kernel<<<dim3(24, 24, 12), blkT, 0, stream>>>(wq_w,  wqkvaT, 768, 768,  0,   (size_t)1024 * 768);
    transpose_cvt_kernel<<<dim3(8,  24, 12), blkT, 0, stream>>>(kva_w, wqkvaT, 768, 256,  768, (size_t)1024 * 768);
    transpose_cvt_kernel<<<dim3(48, 8,  12), blkT, 0, stream>>>(kvb_w, kvbT,   256, 1536, 0,   (size_t)1536 * 256);
    transpose_cvt_kernel<<<dim3(24, 24, 12), blkT, 0, stream>>>(out_w, outT,   768, 768,  0,   (size_t)768 * 768);
    transpose_cvt_kernel<<<dim3(96, 24, 12), blkT, 0, stream>>>(fc_w,  fcT,    768, 3072, 0,   (size_t)3072 * 768);
    transpose_cvt_kernel<<<dim3(24, 96, 12), blkT, 0, stream>>>(proj_w, projT, 3072, 768, 0,   (size_t)768 * 3072);
    cvt_wte_kernel<<<37728, 256, 0, stream>>>(wte, wteB);
    rope_tables_kernel<<<128, 256, 0, stream>>>(cosT, sinT);
    embed_kernel<<<6144, 256, 0, stream>>>(idxp, wte, wpe, x);

    for (int l = 0; l < 12; ++l) {
        ln_kernel<<<2048, 256, 0, stream>>>(x, ln1_w + l * 768, ln1_b + l * 768, h);
        // fused q | kv_latent  (N = 768 + 256)
        gemmT<64, 8><<<dim3(32, 8), 256, 0, stream>>>(
            h, 768, wqkvaT + (size_t)l * 1024 * 768, 768,
            768, 768, 1024, wq_b + l * 768, kva_b + l * 256,
            qbuf, 768, lat, 256, 0, nullptr, nullptr, 0, 0);
        // kv = lat @ kvb: K part -> kvbuf rows, V part -> vT transposed
        gemmT<64, 8><<<dim3(32, 12), 256, 0, stream>>>(
            lat, 256, kvbT + (size_t)l * 1536 * 256, 256,
            256, 768, 1536, kvb_b + l * 1536, kvb_b + l * 1536 + 768,
            kvbuf, 768, vTb, 0, 1, nullptr, nullptr, 0, 0);
        rope_apply2_kernel<<<6144, 256, 0, stream>>>(qbuf, kvbuf, cosT, sinT);
        attn_mfma<<<dim3(16, 24), 256, 0, stream>>>(qbuf, kvbuf, vTb, attnb);
        gemmT<64, 4><<<dim3(32, 12), 256, 0, stream>>>(
            attnb, 768, outT + (size_t)l * 768 * 768, 768,
            768, 768, 768, out_b + l * 768, nullptr,
            nullptr, 0, nullptr, 0, 0, x, x, 768, 0);
        ln_kernel<<<2048, 256, 0, stream>>>(x, ln2_w + l * 768, ln2_b + l * 768, h);
        gemmT<128, 8><<<dim3(16, 24), 256, 0, stream>>>(
            h, 768, fcT + (size_t)l * 3072 * 768, 768,
            768, 3072, 3072, fc_b + l * 3072, nullptr,
            fca, 3072, nullptr, 0, 0, nullptr, nullptr, 0, 1);
        gemmT<64, 4><<<dim3(32, 12), 256, 0, stream>>>(
            fca, 3072, projT + (size_t)l * 768 * 3072, 3072,
            3072, 768, 768, proj_b + l * 768, nullptr,
            nullptr, 0, nullptr, 0, 0, x, x, 768, 0);
    }
    ln_kernel<<<2048, 256, 0, stream>>>(x, lnf_w, lnf_b, h);
    gemmT<128, 8><<<dim3(16, 393), 256, 0, stream>>>(
        h, 768, wteB, 768,
        768, 50304, 50257, nullptr, nullptr,
        nullptr, 0, nullptr, 0, 0, nullptr, (float*)d_out, 50257, 0);
}

// Round 6
// 2168.015 us; speedup vs baseline: 1.4132x; 1.0445x over previous
//
#include <hip/hip_runtime.h>
#include <cstdint>
#include <cstddef>

// GPT2-MLA forward, MI355X. Round 6: 512-thread 8-wave GEMM for fc/lm_head
// (2-deep counted-vmcnt prefetch kept), RoPE fused into qkva/kvb epilogues,
// out/proj at NF=8. B=2,T=1024,D=768,L=12,H=12,HD=64,DL=256,V=50257(pad 50304)

typedef unsigned short ushortT;
typedef __bf16 bf16x8 __attribute__((ext_vector_type(8)));
typedef float f32x4 __attribute__((ext_vector_type(4)));
typedef unsigned short us8 __attribute__((ext_vector_type(8)));

#define NHEAD 12
#define T_SEQ 1024

__device__ __forceinline__ float bf2f(unsigned short u) {
    union { unsigned int i; float f; } v; v.i = ((unsigned int)u) << 16; return v.f;
}
__device__ __forceinline__ unsigned short f2bf(float f) {
    union { float f; unsigned int i; } v; v.f = f;
    unsigned int r = v.i + 0x7fffu + ((v.i >> 16) & 1u);
    return (unsigned short)(r >> 16);
}
__device__ __forceinline__ unsigned int pack2(float a, float b) {
    return (unsigned int)f2bf(a) | ((unsigned int)f2bf(b) << 16);
}
__device__ __forceinline__ void gload_lds16(const void* g, void* l) {
    __builtin_amdgcn_global_load_lds((__attribute__((address_space(1))) void*)g,
                                     (__attribute__((address_space(3))) void*)l, 16, 0, 0);
}
template <int N>
__device__ __forceinline__ void wait_vmcnt() {
    if constexpr (N == 8)      asm volatile("s_waitcnt vmcnt(8)" ::: "memory");
    else if constexpr (N == 6) asm volatile("s_waitcnt vmcnt(6)" ::: "memory");
    else if constexpr (N == 4) asm volatile("s_waitcnt vmcnt(4)" ::: "memory");
    else                       asm volatile("s_waitcnt vmcnt(0)" ::: "memory");
}

// ---------------- weight convert / transpose ----------------
__global__ void transpose_cvt_kernel(const float* __restrict__ in, ushortT* __restrict__ outp,
                                     int K, int N, int outRowOff, size_t outLS) {
    __shared__ float tile[32][33];
    const int tx = threadIdx.x, ty = threadIdx.y;
    const int n0 = blockIdx.x * 32, k0 = blockIdx.y * 32;
    const float* src = in + (size_t)blockIdx.z * K * N;
#pragma unroll
    for (int j = 0; j < 4; ++j)
        tile[ty + j * 8][tx] = src[(size_t)(k0 + ty + j * 8) * N + n0 + tx];
    __syncthreads();
    ushortT* dst = outp + (size_t)blockIdx.z * outLS;
#pragma unroll
    for (int j = 0; j < 4; ++j)
        dst[(size_t)(outRowOff + n0 + ty + j * 8) * K + k0 + tx] = f2bf(tile[tx][ty + j * 8]);
}

__global__ void cvt_wte_kernel(const float* __restrict__ in, ushortT* __restrict__ outp) {
    size_t i4 = (size_t)blockIdx.x * 256 + threadIdx.x;
    ushort4 o;
    if (i4 < 9649344) {
        float4 v = ((const float4*)in)[i4];
        o.x = f2bf(v.x); o.y = f2bf(v.y); o.z = f2bf(v.z); o.w = f2bf(v.w);
    } else { o.x = 0; o.y = 0; o.z = 0; o.w = 0; }
    ((ushort4*)outp)[i4] = o;
}

// ---------------- embedding ----------------
__global__ void embed_kernel(const int* __restrict__ idx, const float* __restrict__ wte,
                             const float* __restrict__ wpe, float* __restrict__ x) {
    int i = blockIdx.x * 256 + threadIdx.x;
    int row = i / 768, d = i - row * 768;
    int t = row & 1023;
    x[i] = wte[(size_t)idx[row] * 768 + d] + wpe[(size_t)t * 768 + d];
}

// ---------------- rope tables ----------------
__global__ void rope_tables_kernel(float* __restrict__ cosT, float* __restrict__ sinT) {
    int i = blockIdx.x * 256 + threadIdx.x;  // 1024*32
    int t = i >> 5, f = i & 31;
    float invf = exp2f(-(float)f * (13.287712379549449f / 32.0f));
    float ang = (float)t * invf;
    cosT[i] = cosf(ang);
    sinT[i] = sinf(ang);
}

// ---------------- layernorm ----------------
__global__ __launch_bounds__(256) void ln_kernel(const float* __restrict__ x,
                                                 const float* __restrict__ wg,
                                                 const float* __restrict__ bg,
                                                 ushortT* __restrict__ outp) {
    const int row = blockIdx.x, tid = threadIdx.x;
    const float* xr = x + (size_t)row * 768;
    float v0 = xr[tid], v1 = xr[tid + 256], v2 = xr[tid + 512];
    float s = v0 + v1 + v2;
    float ss = v0 * v0 + v1 * v1 + v2 * v2;
#pragma unroll
    for (int off = 32; off >= 1; off >>= 1) {
        s += __shfl_xor(s, off);
        ss += __shfl_xor(ss, off);
    }
    __shared__ float sb[4], ssb[4];
    if ((tid & 63) == 0) { sb[tid >> 6] = s; ssb[tid >> 6] = ss; }
    __syncthreads();
    float S = sb[0] + sb[1] + sb[2] + sb[3];
    float SS = ssb[0] + ssb[1] + ssb[2] + ssb[3];
    const float mean = S * (1.0f / 768.0f);
    float var = SS * (1.0f / 768.0f) - mean * mean;
    const float rs = rsqrtf(var + 1e-5f);
    ushortT* orow = outp + (size_t)row * 768;
    orow[tid]       = f2bf((v0 - mean) * rs * wg[tid]       + bg[tid]);
    orow[tid + 256] = f2bf((v1 - mean) * rs * wg[tid + 256] + bg[tid + 256]);
    orow[tid + 512] = f2bf((v2 - mean) * rs * wg[tid + 512] + bg[tid + 512]);
}

// ---------------- GEMM: C[2048 x N] = A[2048 x K] @ Bt[N x K]^T ----------------
// BM x (NF*16) tile, BK=64. NTHR=256: 4 waves stacked in M. NTHR=512: 8 waves
// 4M x 2N (wave = 32 rows x NF*8 cols). Double-buffered LDS + XOR swizzle.
// 2-deep prefetch with COUNTED vmcnt (raw s_barrier) - tile t+2 in flight
// across barrier, only t+1 waited. ROPE: fuse RoPE into epilogue for cols<768
// (partner col d+-32 lives in acc[.][nf+-2] of the SAME thread).
template <int BM, int NF, int NTHR, bool ROPE>
__global__ __launch_bounds__(NTHR) void gemmT(
    const ushortT* __restrict__ A, int lda,
    const ushortT* __restrict__ Bt, int ldb,
    int K, int CS, int Nstore,
    const float* __restrict__ bias0, const float* __restrict__ bias1,
    ushortT* __restrict__ outB0, int ld0,
    ushortT* __restrict__ outB1, int ld1, int mode1,
    const float* __restrict__ resid, float* __restrict__ outF, int ldF,
    int act, const float* __restrict__ cosT, const float* __restrict__ sinT) {
    constexpr int NW = NTHR / 64;
    constexpr int WC = (NTHR == 512) ? 2 : 1;   // waves along N
    constexpr int WR = NW / WC;                 // waves along M
    constexpr int WMR = BM / WR;                // rows per wave
    constexpr int MF = WMR / 16;
    constexpr int NFh = NF / WC;
    constexpr int ABYTES = BM * 128;            // per-buffer A bytes (BK=64)
    constexpr int BBYTES = NF * 2048;
    constexpr int BUFB = ABYTES + BBYTES;
    constexpr int A_LOADS = (BM * 8) / NTHR;
    constexpr int B_LOADS = (NF * 128) / NTHR;
    constexpr int S = A_LOADS + B_LOADS;
    __shared__ __align__(16) char lds[2 * BUFB];
    const int tid = threadIdx.x;
    const int w = tid >> 6, lane = tid & 63;
    const int wm = (WC == 2) ? (w >> 1) : w;
    const int wn = (WC == 2) ? (w & 1) : 0;
    // bijective XCD-chunked swizzle (m204)
    const int gx = gridDim.x;
    const int nwg = gx * gridDim.y;
    const int flat = blockIdx.x + gx * blockIdx.y;
    const int xcd = flat & 7, loc = flat >> 3;
    const int qq = nwg >> 3, rr_ = nwg & 7;
    const int swz = (xcd < rr_ ? xcd * (qq + 1) : rr_ * (qq + 1) + (xcd - rr_) * qq) + loc;
    const int m0 = (swz % gx) * BM, n0 = (swz / gx) * NF * 16;
    const int fr = lane & 15, kg = lane >> 4;
    const size_t ldaB = (size_t)lda * 2, ldbB = (size_t)ldb * 2;
    const char* Ab = (const char*)A;
    const char* Bb = (const char*)Bt;
    f32x4 acc[MF][NFh] = {};

    auto stage = [&](int buf, int t) {
        const size_t ktB = (size_t)t << 7;
        char* As_ = lds + buf * BUFB;
        char* Bs_ = As_ + ABYTES;
#pragma unroll
        for (int jj = 0; jj < A_LOADS; ++jj) {
            const int i = tid + jj * NTHR;
            const int r = i >> 3, c = i & 7, cc = c ^ (r & 7);
            gload_lds16(Ab + (size_t)(m0 + r) * ldaB + ktB + cc * 16, As_ + i * 16);
        }
#pragma unroll
        for (int jj = 0; jj < B_LOADS; ++jj) {
            const int i = tid + jj * NTHR;
            const int r = i >> 3, c = i & 7, cc = c ^ (r & 7);
            gload_lds16(Bb + (size_t)(n0 + r) * ldbB + ktB + cc * 16, Bs_ + i * 16);
        }
    };

    const int nk = K >> 6;
    stage(0, 0);
    if (nk > 1) { stage(1, 1); wait_vmcnt<S>(); }
    else        { wait_vmcnt<0>(); }
    __builtin_amdgcn_s_barrier();

    for (int t = 0; t < nk; ++t) {
        const int cur = t & 1;
        const char* As_ = lds + cur * BUFB;
        const char* Bs_ = As_ + ABYTES;
        bf16x8 af[MF][2], bfr[NFh][2];
#pragma unroll
        for (int mf = 0; mf < MF; ++mf) {
            const int row = wm * WMR + mf * 16 + fr;
#pragma unroll
            for (int ks = 0; ks < 2; ++ks)
                af[mf][ks] = *(const bf16x8*)(As_ + row * 128 + (((ks * 4 + kg) ^ (row & 7)) << 4));
        }
#pragma unroll
        for (int nf = 0; nf < NFh; ++nf) {
            const int row = wn * (NFh * 16) + nf * 16 + fr;
#pragma unroll
            for (int ks = 0; ks < 2; ++ks)
                bfr[nf][ks] = *(const bf16x8*)(Bs_ + row * 128 + (((ks * 4 + kg) ^ (row & 7)) << 4));
        }
        if (t + 2 < nk) {
            asm volatile("s_waitcnt lgkmcnt(0)" ::: "memory");  // reads of buf[cur] done
            __builtin_amdgcn_s_barrier();                       // ... in ALL waves
            stage(cur, t + 2);                                  // overwrite buf[cur]
        }
#pragma unroll
        for (int ks = 0; ks < 2; ++ks)
#pragma unroll
            for (int nf = 0; nf < NFh; ++nf)
#pragma unroll
                for (int mf = 0; mf < MF; ++mf)
                    acc[mf][nf] = __builtin_amdgcn_mfma_f32_16x16x32_bf16(
                        af[mf][ks], bfr[nf][ks], acc[mf][nf], 0, 0, 0);
        if (t + 1 < nk) {
            if (t + 2 < nk) wait_vmcnt<S>();  // t+1 landed; t+2 stays in flight
            else            wait_vmcnt<0>();
            __builtin_amdgcn_s_barrier();
        }
    }

    if constexpr (ROPE) {
        // requires MF==1, WC==1 (BM=64, 256 thr). Bias, then RoPE for cols<768.
        float vv[NF][4];
#pragma unroll
        for (int nf = 0; nf < NF; ++nf) {
            const int gcol = n0 + nf * 16 + fr;
            float bv = (gcol < CS) ? (bias0 ? bias0[gcol] : 0.0f)
                                   : (bias1 ? bias1[gcol - CS] : 0.0f);
#pragma unroll
            for (int j = 0; j < 4; ++j) vv[nf][j] = acc[0][nf][j] + bv;
        }
        if (n0 < 768) {  // whole 128-col panel is in rope region (head-aligned)
#pragma unroll
            for (int j = 0; j < 4; ++j) {
                const int grow = m0 + wm * WMR + kg * 4 + j;
                const int t = grow & 1023;
                const float c0 = cosT[t * 32 + fr],      s0 = sinT[t * 32 + fr];
                const float c1 = cosT[t * 32 + 16 + fr], s1 = sinT[t * 32 + 16 + fr];
#pragma unroll
                for (int base = 0; base < NF; base += 4) {  // 2 heads per panel
                    float x1 = vv[base + 0][j], x2 = vv[base + 2][j];
                    vv[base + 0][j] = x1 * c0 - x2 * s0;
                    vv[base + 2][j] = x2 * c0 + x1 * s0;
                    float y1 = vv[base + 1][j], y2 = vv[base + 3][j];
                    vv[base + 1][j] = y1 * c1 - y2 * s1;
                    vv[base + 3][j] = y2 * c1 + y1 * s1;
                }
            }
        }
#pragma unroll
        for (int nf = 0; nf < NF; ++nf) {
            const int gcol = n0 + nf * 16 + fr;
            if (gcol >= Nstore) continue;
#pragma unroll
            for (int j = 0; j < 4; ++j) {
                const int grow = m0 + wm * WMR + kg * 4 + j;
                const float v = vv[nf][j];
                if (gcol < CS) {
                    if (outB0) outB0[(size_t)grow * ld0 + gcol] = f2bf(v);
                } else if (outB1) {
                    if (mode1 == 0) {
                        outB1[(size_t)grow * ld1 + gcol - CS] = f2bf(v);
                    } else {
                        const int bb = grow >> 10, tt = grow & 1023;
                        const int hd = gcol - CS;
                        outB1[((size_t)((bb * 12 + (hd >> 6)) * 64 + (hd & 63)) << 10) + tt] = f2bf(v);
                    }
                }
            }
        }
    } else {
        // epilogue: frag row = kg*4+j, col = fr
#pragma unroll
        for (int mf = 0; mf < MF; ++mf) {
#pragma unroll
            for (int nf = 0; nf < NFh; ++nf) {
                const int gcol = n0 + wn * (NFh * 16) + nf * 16 + fr;
                if (gcol >= Nstore) continue;
                float bv = 0.0f;
                if (gcol < CS) { if (bias0) bv = bias0[gcol]; }
                else           { if (bias1) bv = bias1[gcol - CS]; }
#pragma unroll
                for (int j = 0; j < 4; ++j) {
                    const int grow = m0 + wm * WMR + mf * 16 + kg * 4 + j;
                    float v = acc[mf][nf][j] + bv;
                    if (resid) v += resid[(size_t)grow * ldF + gcol];
                    if (act) v = 0.5f * v * (1.0f + erff(v * 0.70710678118654752f));
                    if (outF) outF[(size_t)grow * ldF + gcol] = v;
                    if (gcol < CS) {
                        if (outB0) outB0[(size_t)grow * ld0 + gcol] = f2bf(v);
                    } else if (outB1) {
                        if (mode1 == 0) {
                            outB1[(size_t)grow * ld1 + gcol - CS] = f2bf(v);
                        } else {
                            const int bb = grow >> 10, tt = grow & 1023;
                            const int hd = gcol - CS;
                            outB1[((size_t)((bb * 12 + (hd >> 6)) * 64 + (hd & 63)) << 10) + tt] = f2bf(v);
                        }
                    }
                }
            }
        }
    }
}

// ---------------- MFMA flash attention ----------------
// Grid (16, 24): x = q-tile of 64 rows, y = (b,h). 4 waves, wave w owns 16 q rows.
// S^T = mfma(Kfrag, Qfrag) -> lane (fr,kg) holds q-row fr's scores (s = n*16+kg*4+j).
// Online softmax per-lane; P exchanged via per-wave LDS row buffer; PV = mfma(P, V^T).
__global__ __launch_bounds__(256) void attn_mfma(const ushortT* __restrict__ q,
                                                 const ushortT* __restrict__ kbuf,
                                                 const ushortT* __restrict__ vT,
                                                 ushortT* __restrict__ attnb) {
    __shared__ __align__(16) char lds[41472];  // K dbuf 16K | V dbuf 16K | P 4x2176
    const int tid = threadIdx.x, w = tid >> 6, lane = tid & 63;
    const int fr = lane & 15, kg = lane >> 4;
    const int b = blockIdx.y / NHEAD, h = blockIdx.y % NHEAD;
    const int qb = blockIdx.x * 64;
    const int q0 = qb + w * 16;
    const int nst = (qb >> 6) + 1, diag = qb >> 6;

    const ushortT* qrow = q + ((size_t)(b * 1024 + q0 + fr) * 768 + h * 64);
    const bf16x8 qf0 = *(const bf16x8*)(qrow + kg * 8);
    const bf16x8 qf1 = *(const bf16x8*)(qrow + 32 + kg * 8);

    const char* kgb = (const char*)kbuf + ((size_t)(b * 1024) * 768 + h * 64) * 2;
    const char* vgb = (const char*)vT + ((size_t)(b * 12 + h) * 65536) * 2;
    char* Pw = lds + 32768 + w * 2176 + fr * 136;

    auto stage = [&](int buf, int st) {
#pragma unroll
        for (int jj = 0; jj < 2; ++jj) {
            const int i = tid + jj * 256;
            const int r = i >> 3, c = i & 7, cc = c ^ (r & 7);
            gload_lds16(kgb + (size_t)(st * 64 + r) * 1536 + cc * 16, lds + buf * 8192 + i * 16);
            gload_lds16(vgb + (size_t)r * 2048 + st * 128 + cc * 16, lds + 16384 + buf * 8192 + i * 16);
        }
    };

    float m_r = -1e30f, l_r = 0.0f;
    f32x4 o[4] = {};

    stage(0, 0);
    __syncthreads();
    for (int st = 0; st < nst; ++st) {
        const int cur = st & 1;
        if (st + 1 < nst) stage(cur ^ 1, st + 1);
        const char* Kd = lds + cur * 8192;
        const char* Vd = lds + 16384 + cur * 8192;

        // S^T frags: sfr[n] rows s = n*16+kg*4+j, col q=fr
        f32x4 sfr[4];
#pragma unroll
        for (int n = 0; n < 4; ++n) {
            const int row = n * 16 + fr;
            bf16x8 k0 = *(const bf16x8*)(Kd + row * 128 + ((kg ^ (row & 7)) << 4));
            bf16x8 k1 = *(const bf16x8*)(Kd + row * 128 + (((4 + kg) ^ (row & 7)) << 4));
            f32x4 sa = {0.0f, 0.0f, 0.0f, 0.0f};
            sa = __builtin_amdgcn_mfma_f32_16x16x32_bf16(k0, qf0, sa, 0, 0, 0);
            sa = __builtin_amdgcn_mfma_f32_16x16x32_bf16(k1, qf1, sa, 0, 0, 0);
            sfr[n] = sa;
        }
        const int qoff = w * 16 + fr;
#pragma unroll
        for (int n = 0; n < 4; ++n)
#pragma unroll
            for (int j = 0; j < 4; ++j) {
                float v = sfr[n][j] * 0.125f;
                if (st == diag && (n * 16 + kg * 4 + j) > qoff) v = -1e30f;
                sfr[n][j] = v;
            }
        // online softmax (state per lane, q = fr)
        float tm = -1e30f;
#pragma unroll
        for (int n = 0; n < 4; ++n)
#pragma unroll
            for (int j = 0; j < 4; ++j) tm = fmaxf(tm, sfr[n][j]);
        tm = fmaxf(tm, __shfl_xor(tm, 16));
        tm = fmaxf(tm, __shfl_xor(tm, 32));
        const float mnew = fmaxf(m_r, tm);
        const float fac = __expf(m_r - mnew);
        m_r = mnew;
        l_r *= fac;
        const float ff0 = __shfl(fac, kg * 4 + 0);
        const float ff1 = __shfl(fac, kg * 4 + 1);
        const float ff2 = __shfl(fac, kg * 4 + 2);
        const float ff3 = __shfl(fac, kg * 4 + 3);
#pragma unroll
        for (int nf = 0; nf < 4; ++nf) {
            o[nf][0] *= ff0; o[nf][1] *= ff1; o[nf][2] *= ff2; o[nf][3] *= ff3;
        }
        // exp, pack to bf16, write P rows to per-wave LDS
#pragma unroll
        for (int n = 0; n < 4; ++n) {
            float e0 = __expf(sfr[n][0] - mnew);
            float e1 = __expf(sfr[n][1] - mnew);
            float e2 = __expf(sfr[n][2] - mnew);
            float e3 = __expf(sfr[n][3] - mnew);
            l_r += (e0 + e1) + (e2 + e3);
            uint2 pv;
            pv.x = pack2(e0, e1);
            pv.y = pack2(e2, e3);
            *(uint2*)(Pw + n * 32 + kg * 8) = pv;
        }
        // PV: A = P[q=fr][s], B = V^T[d][s]
#pragma unroll
        for (int ks = 0; ks < 2; ++ks) {
            uint2 a0 = *(const uint2*)(Pw + ks * 64 + kg * 16);
            uint2 a1 = *(const uint2*)(Pw + ks * 64 + kg * 16 + 8);
            union { uint4 u; bf16x8 v; } pa;
            pa.u = make_uint4(a0.x, a0.y, a1.x, a1.y);
#pragma unroll
            for (int nf = 0; nf < 4; ++nf) {
                const int row = nf * 16 + fr;
                bf16x8 vf = *(const bf16x8*)(Vd + row * 128 + (((ks * 4 + kg) ^ (row & 7)) << 4));
                o[nf] = __builtin_amdgcn_mfma_f32_16x16x32_bf16(pa.v, vf, o[nf], 0, 0, 0);
            }
        }
        __syncthreads();
    }

    l_r += __shfl_xor(l_r, 16);
    l_r += __shfl_xor(l_r, 32);
    const float inv = 1.0f / l_r;
    const float iv0 = __shfl(inv, kg * 4 + 0);
    const float iv1 = __shfl(inv, kg * 4 + 1);
    const float iv2 = __shfl(inv, kg * 4 + 2);
    const float iv3 = __shfl(inv, kg * 4 + 3);
#pragma unroll
    for (int nf = 0; nf < 4; ++nf) {
        const size_t base = (size_t)(b * 1024 + q0) * 768 + h * 64 + nf * 16 + fr;
        attnb[base + (size_t)(kg * 4 + 0) * 768] = f2bf(o[nf][0] * iv0);
        attnb[base + (size_t)(kg * 4 + 1) * 768] = f2bf(o[nf][1] * iv1);
        attnb[base + (size_t)(kg * 4 + 2) * 768] = f2bf(o[nf][2] * iv2);
        attnb[base + (size_t)(kg * 4 + 3) * 768] = f2bf(o[nf][3] * iv3);
    }
}

// ---------------- host ----------------
extern "C" void kernel_launch(void* const* d_in, const int* in_sizes, int n_in,
                              void* d_out, int out_size, void* d_ws, size_t ws_size,
                              hipStream_t stream) {
    (void)in_sizes; (void)n_in; (void)out_size; (void)ws_size;
    const int*   idxp   = (const int*)d_in[0];
    const float* wte    = (const float*)d_in[1];
    const float* wpe    = (const float*)d_in[2];
    const float* ln1_w  = (const float*)d_in[3];
    const float* ln1_b  = (const float*)d_in[4];
    const float* wq_w   = (const float*)d_in[5];
    const float* wq_b   = (const float*)d_in[6];
    const float* kva_w  = (const float*)d_in[7];
    const float* kva_b  = (const float*)d_in[8];
    const float* kvb_w  = (const float*)d_in[9];
    const float* kvb_b  = (const float*)d_in[10];
    const float* out_w  = (const float*)d_in[11];
    const float* out_b  = (const float*)d_in[12];
    const float* ln2_w  = (const float*)d_in[13];
    const float* ln2_b  = (const float*)d_in[14];
    const float* fc_w   = (const float*)d_in[15];
    const float* fc_b   = (const float*)d_in[16];
    const float* proj_w = (const float*)d_in[17];
    const float* proj_b = (const float*)d_in[18];
    const float* lnf_w  = (const float*)d_in[19];
    const float* lnf_b  = (const float*)d_in[20];

    char* ws = (char*)d_ws;
    size_t off = 0;
    auto alloc = [&](size_t bytes) -> char* {
        char* p = ws + off;
        off += (bytes + 255) & ~(size_t)255;
        return p;
    };
    ushortT* wqkvaT = (ushortT*)alloc((size_t)12 * 1024 * 768 * 2);
    ushortT* kvbT   = (ushortT*)alloc((size_t)12 * 1536 * 256 * 2);
    ushortT* outT   = (ushortT*)alloc((size_t)12 * 768 * 768 * 2);
    ushortT* fcT    = (ushortT*)alloc((size_t)12 * 3072 * 768 * 2);
    ushortT* projT  = (ushortT*)alloc((size_t)12 * 768 * 3072 * 2);
    ushortT* wteB   = (ushortT*)alloc((size_t)50304 * 768 * 2);
    float* cosT = (float*)alloc((size_t)1024 * 32 * 4);
    float* sinT = (float*)alloc((size_t)1024 * 32 * 4);
    float*   x     = (float*)alloc((size_t)2048 * 768 * 4);
    ushortT* h     = (ushortT*)alloc((size_t)2048 * 768 * 2);
    ushortT* qbuf  = (ushortT*)alloc((size_t)2048 * 768 * 2);
    ushortT* lat   = (ushortT*)alloc((size_t)2048 * 256 * 2);
    ushortT* kvbuf = (ushortT*)alloc((size_t)2048 * 768 * 2);   // K only (roped)
    ushortT* vTb   = (ushortT*)alloc((size_t)24 * 64 * 1024 * 2);  // [b][h][d][t]
    ushortT* attnb = (ushortT*)alloc((size_t)2048 * 768 * 2);
    ushortT* fca   = (ushortT*)alloc((size_t)2048 * 3072 * 2);

    const dim3 blkT(32, 8);
    transpose_cvt_kernel<<<dim3(24, 24, 12), blkT, 0, stream>>>(wq_w,  wqkvaT, 768, 768,  0,   (size_t)1024 * 768);
    transpose_cvt_kernel<<<dim3(8,  24, 12), blkT, 0, stream>>>(kva_w, wqkvaT, 768, 256,  768, (size_t)1024 * 768);
    transpose_cvt_kernel<<<dim3(48, 8,  12), blkT, 0, stream>>>(kvb_w, kvbT,   256, 1536, 0,   (size_t)1536 * 256);
    transpose_cvt_kernel<<<dim3(24, 24, 12), blkT, 0, stream>>>(out_w, outT,   768, 768,  0,   (size_t)768 * 768);
    transpose_cvt_kernel<<<dim3(96, 24, 12), blkT, 0, stream>>>(fc_w,  fcT,    768, 3072, 0,   (size_t)3072 * 768);
    transpose_cvt_kernel<<<dim3(24, 96, 12), blkT, 0, stream>>>(proj_w, projT, 3072, 768, 0,   (size_t)768 * 3072);
    cvt_wte_kernel<<<37728, 256, 0, stream>>>(wte, wteB);
    rope_tables_kernel<<<128, 256, 0, stream>>>(cosT, sinT);
    embed_kernel<<<6144, 256, 0, stream>>>(idxp, wte, wpe, x);

    for (int l = 0; l < 12; ++l) {
        ln_kernel<<<2048, 256, 0, stream>>>(x, ln1_w + l * 768, ln1_b + l * 768, h);
        // fused q | kv_latent  (N = 768 + 256), RoPE fused on q cols
        gemmT<64, 8, 256, true><<<dim3(32, 8), 256, 0, stream>>>(
            h, 768, wqkvaT + (size_t)l * 1024 * 768, 768,
            768, 768, 1024, wq_b + l * 768, kva_b + l * 256,
            qbuf, 768, lat, 256, 0, nullptr, nullptr, 0, 0, cosT, sinT);
        // kv = lat @ kvb: K part (roped) -> kvbuf rows, V part -> vT transposed
        gemmT<64, 8, 256, true><<<dim3(32, 12), 256, 0, stream>>>(
            lat, 256, kvbT + (size_t)l * 1536 * 256, 256,
            256, 768, 1536, kvb_b + l * 1536, kvb_b + l * 1536 + 768,
            kvbuf, 768, vTb, 0, 1, nullptr, nullptr, 0, 0, cosT, sinT);
        attn_mfma<<<dim3(16, 24), 256, 0, stream>>>(qbuf, kvbuf, vTb, attnb);
        gemmT<64, 8, 256, false><<<dim3(32, 6), 256, 0, stream>>>(
            attnb, 768, outT + (size_t)l * 768 * 768, 768,
            768, 768, 768, out_b + l * 768, nullptr,
            nullptr, 0, nullptr, 0, 0, x, x, 768, 0, nullptr, nullptr);
        ln_kernel<<<2048, 256, 0, stream>>>(x, ln2_w + l * 768, ln2_b + l * 768, h);
        gemmT<128, 8, 512, false><<<dim3(16, 24), 512, 0, stream>>>(
            h, 768, fcT + (size_t)l * 3072 * 768, 768,
            768, 3072, 3072, fc_b + l * 3072, nullptr,
            fca, 3072, nullptr, 0, 0, nullptr, nullptr, 0, 1, nullptr, nullptr);
        gemmT<64, 8, 256, false><<<dim3(32, 6), 256, 0, stream>>>(
            fca, 3072, projT + (size_t)l * 768 * 3072, 3072,
            3072, 768, 768, proj_b + l * 768, nullptr,
            nullptr, 0, nullptr, 0, 0, x, x, 768, 0, nullptr, nullptr);
    }
    ln_kernel<<<2048, 256, 0, stream>>>(x, lnf_w, lnf_b, h);
    gemmT<128, 8, 512, false><<<dim3(16, 393), 512, 0, stream>>>(
        h, 768, wteB, 768,
        768, 50304, 50257, nullptr, nullptr,
        nullptr, 0, nullptr, 0, 0, nullptr, (float*)d_out, 50257, 0, nullptr, nullptr);
}